// Round 7
// baseline (742.600 us; speedup 1.0000x reference)
//
#include <hip/hip_runtime.h>
#include <math.h>

typedef __bf16 bf16x8 __attribute__((ext_vector_type(8)));
typedef __bf16 bf16x4 __attribute__((ext_vector_type(4)));
typedef float  f32x4  __attribute__((ext_vector_type(4)));
typedef unsigned long long u64;
typedef u64 u64x2 __attribute__((ext_vector_type(2)));

__device__ __forceinline__ float gelu_f(float x) {
  const float k0 = 0.7978845608028654f;
  const float k1 = 0.044715f;
  float x3 = x * x * x;
  return 0.5f * x * (1.0f + tanhf(k0 * (x + k1 * x3)));
}

// coherent (agent-scope, IF$-backed) accessors: bypass non-coherent per-XCD L2
__device__ __forceinline__ u64 cload8(const void* p) {
  return __hip_atomic_load((u64*)p, __ATOMIC_RELAXED, __HIP_MEMORY_SCOPE_AGENT);
}
__device__ __forceinline__ void cstore_bf16(__bf16* p, __bf16 h) {
  __hip_atomic_store((short*)p, __builtin_bit_cast(short, h),
                     __ATOMIC_RELAXED, __HIP_MEMORY_SCOPE_AGENT);
}

// ---------------- prep: pool + weight transposes + Wv pack + y conv + beff ----------------
__global__ __launch_bounds__(256) void prep_kernel(
    const float* __restrict__ xe,
    const float* __restrict__ Wpi, const float* __restrict__ Wpa,
    const float* __restrict__ Wc,  const float* __restrict__ w1f,
    const float* __restrict__ w2f, const float* __restrict__ wo,
    const float* __restrict__ wqkv, const float* __restrict__ y,
    const float* __restrict__ bqkv, const float* __restrict__ bo,
    __bf16* __restrict__ xp_b,
    __bf16* __restrict__ WpiT, __bf16* __restrict__ WpaT,
    __bf16* __restrict__ WcabT, __bf16* __restrict__ WccT,
    __bf16* __restrict__ w1T,  __bf16* __restrict__ w2T,
    __bf16* __restrict__ woT,  __bf16* __restrict__ Wv_b,
    __bf16* __restrict__ y_b,  float* __restrict__ beff)
{
  int bid = blockIdx.x;
  int tid = threadIdx.x;
  if (bid < 512) {               // mean pool (128,512,1024) -> (128,1024) bf16
    int b = bid >> 2;
    int c = (bid & 3) * 256 + tid;
    const float* p = xe + (size_t)b * 512 * 1024 + c;
    float s = 0.f;
#pragma unroll 16
    for (int i = 0; i < 512; ++i) s += p[(size_t)i * 1024];
    xp_b[b * 1024 + c] = (__bf16)(s * (1.f / 512.f));
  } else if (bid < 6528) {       // transposes fp32 -> bf16 (N x K layout)
    int t = bid - 512;
    const float* src; __bf16* dst; int R, C;
    if      (t < 512)  {            src = Wpi;            dst = WpiT;          R = 1024; C = 512;  }
    else if (t < 640)  { t -= 512;  src = Wpa;            dst = WpaT;          R = 256;  C = 512;  }
    else if (t < 1152) { t -= 640;  src = Wc;             dst = WcabT;         R = 1024; C = 512;  }
    else if (t < 1408) { t -= 1152; src = Wc + 1024*512;  dst = WccT;          R = 512;  C = 512;  }
    else if (t < 2432) { t -= 1408; src = w1f;            dst = w1T;           R = 512;  C = 2048; }
    else if (t < 3456) { t -= 2432; src = w1f + 512*2048; dst = w1T + 1048576; R = 512;  C = 2048; }
    else if (t < 4480) { t -= 3456; src = w2f;            dst = w2T;           R = 2048; C = 512;  }
    else if (t < 5504) { t -= 4480; src = w2f + 2048*512; dst = w2T + 1048576; R = 2048; C = 512;  }
    else if (t < 5760) { t -= 5504; src = wo;             dst = woT;           R = 512;  C = 512;  }
    else               { t -= 5760; src = wo + 512*512;   dst = woT + 262144;  R = 512;  C = 512;  }
    int nbc = C / 32;
    int r0 = (t / nbc) * 32;
    int c0 = (t % nbc) * 32;
    __shared__ float tt[32][33];
    int tx = tid & 31, ty = tid >> 5;
#pragma unroll
    for (int i = 0; i < 32; i += 8)
      tt[ty + i][tx] = src[(size_t)(r0 + ty + i) * C + c0 + tx];
    __syncthreads();
#pragma unroll
    for (int i = 0; i < 32; i += 8)
      dst[(size_t)(c0 + ty + i) * R + r0 + tx] = (__bf16)tt[tx][ty + i];
  } else if (bid < 6784) {       // Wv pack
    int e0 = ((bid - 6528) * 256 + tid) * 8;
    int l = e0 >> 18, rem = e0 & 262143;
    int m = rem >> 9, k = rem & 511;
    const float* s = wqkv + (size_t)l * 786432 + (size_t)m * 1536 + 1024 + k;
#pragma unroll
    for (int j = 0; j < 8; ++j) Wv_b[e0 + j] = (__bf16)s[j];
  } else if (bid < 6800) {       // y -> bf16
    int e0 = ((bid - 6784) * 256 + tid) * 8;
#pragma unroll
    for (int j = 0; j < 8; ++j) y_b[e0 + j] = (__bf16)y[e0 + j];
  } else {                       // beff[l] = bv @ wo + bo
    int b2 = bid - 6800;
    int l = b2 >> 1;
    int n = (b2 & 1) * 256 + tid;
    const float* bv = bqkv + l * 1536 + 1024;
    const float* w  = wo + (size_t)l * 262144;
    float s = bo[l * 512 + n];
#pragma unroll 8
    for (int k = 0; k < 512; ++k) s += bv[k] * w[(size_t)k * 512 + n];
    beff[l * 512 + n] = s;
  }
}

// ---------------- LDS-tile GEMM (aux only; prep->aux boundary makes normal caching safe) ----
template<int NT, bool BIAS>
__device__ __forceinline__ void gemm32(
    const __bf16* A, const __bf16* Bt, int bm0, int bn0,
    const float* bias, __bf16* outb, int ldo,
    __bf16* AL, __bf16* BL)
{
  const int tid = threadIdx.x;
  constexpr int K = NT * 64;
  const int row = tid >> 3;
  const int kcol = (tid & 7) * 8;

  const __bf16* Ab0 = A + (size_t)(bm0 + row) * K + kcol;
  const __bf16* Bb0 = Bt + (size_t)(bn0 + row) * K + kcol;

  u64 ra0[4], ra1[4], rb0[4], rb1[4];
  auto issue = [&](int t, int s) {
    const __bf16* ap = Ab0 + t * 64;
    const __bf16* bp = Bb0 + t * 64;
    ra0[s] = *(const u64*)ap; ra1[s] = *(const u64*)(ap + 4);
    rb0[s] = *(const u64*)bp; rb1[s] = *(const u64*)(bp + 4);
  };
#pragma unroll
  for (int s = 0; s < 4; ++s) issue(s, s);

  f32x4 acc = {0.f, 0.f, 0.f, 0.f};
  const int wave = tid >> 6, lane = tid & 63;
  const int wr = (wave >> 1) * 16, wc = (wave & 1) * 16;
  const int lr = lane & 15, lk8 = (lane >> 4) * 8;

  for (int ttc = 0; ttc < NT / 4; ++ttc) {
#pragma unroll
    for (int ti = 0; ti < 4; ++ti) {
      const int t = ttc * 4 + ti;
      __bf16* al = AL + (ti & 1) * 2304 + row * 72 + kcol;
      __bf16* bl = BL + (ti & 1) * 2304 + row * 72 + kcol;
      *(u64*)al = ra0[ti]; *(u64*)(al + 4) = ra1[ti];
      *(u64*)bl = rb0[ti]; *(u64*)(bl + 4) = rb1[ti];
      __syncthreads();
      if (t + 4 < NT) issue(t + 4, ti);
      const __bf16* Ar = AL + (ti & 1) * 2304 + (wr + lr) * 72;
      const __bf16* Br = BL + (ti & 1) * 2304 + (wc + lr) * 72;
      bf16x8 a0 = *(const bf16x8*)(Ar + lk8);
      bf16x8 b0v = *(const bf16x8*)(Br + lk8);
      acc = __builtin_amdgcn_mfma_f32_16x16x32_bf16(a0, b0v, acc, 0, 0, 0);
      bf16x8 a1 = *(const bf16x8*)(Ar + 32 + lk8);
      bf16x8 b1v = *(const bf16x8*)(Br + 32 + lk8);
      acc = __builtin_amdgcn_mfma_f32_16x16x32_bf16(a1, b1v, acc, 0, 0, 0);
      __syncthreads();
    }
  }

  const int er = bm0 + wr + (lane >> 4) * 4;
  const int ec = bn0 + wc + lr;
#pragma unroll
  for (int e = 0; e < 4; ++e) {
    float v = acc[e];
    if (BIAS) v += bias[ec];
    outb[(size_t)(er + e) * ldo + ec] = (__bf16)v;
  }
}

// ---------------- aux: Weff GEMMs + projections ----------------
__global__ __launch_bounds__(256) void aux_kernel(
    const __bf16* __restrict__ woT, const __bf16* __restrict__ Wv_b,
    const __bf16* __restrict__ xp_b, const __bf16* __restrict__ y_b,
    const __bf16* __restrict__ WpiT, const __bf16* __restrict__ WpaT,
    const float* __restrict__ bpi, const float* __restrict__ bpa,
    __bf16* __restrict__ WeffT, __bf16* __restrict__ xy_b)
{
  __shared__ __bf16 AL[2 * 32 * 72];
  __shared__ __bf16 BL[2 * 32 * 72];
  int bid = blockIdx.x;
  if (bid < 512) {        // WeffT[l][n][j] = sum_m woT[l][n][m] * Wv_b[l][j][m]
    int l = bid >> 8, t = bid & 255;
    gemm32<8, false>(woT + l * 262144, Wv_b + l * 262144,
        (t >> 4) * 32, (t & 15) * 32, nullptr, WeffT + l * 262144, 512, AL, BL);
  } else if (bid < 576) { // xy[:, :512] = xp @ Wpi + bpi
    int t = bid - 512;
    gemm32<16, true>(xp_b, WpiT, (t >> 4) * 32, (t & 15) * 32,
        bpi, xy_b, 1024, AL, BL);
  } else {                // xy[:, 512:] = y @ Wpa + bpa
    int t = bid - 576;
    gemm32<4, true>(y_b, WpaT, (t >> 4) * 32, (t & 15) * 32,
        bpa, xy_b + 512, 1024, AL, BL);
  }
}

// ---------------- per-group barrier: parallel slot arrivals + broadcast release ----------------
// slots: 16 ints spaced 32 apart (128B lines); rel: 1 int. Monotonic epochs, memset'd per launch.
__device__ __forceinline__ void groupbar(int* slots, int* rel, int lg, int ep) {
  asm volatile("s_waitcnt vmcnt(0)" ::: "memory");
  __syncthreads();
  const int tid = threadIdx.x;
  if (lg == 0) {
    if (tid >= 1 && tid < 16) {
      while (__hip_atomic_load(slots + tid * 32, __ATOMIC_RELAXED, __HIP_MEMORY_SCOPE_AGENT) < ep)
        __builtin_amdgcn_s_sleep(1);
    }
    __syncthreads();
    if (tid == 0)
      __hip_atomic_store(rel, ep, __ATOMIC_RELAXED, __HIP_MEMORY_SCOPE_AGENT);
  } else {
    if (tid == 0) {
      __hip_atomic_store(slots + lg * 32, ep, __ATOMIC_RELAXED, __HIP_MEMORY_SCOPE_AGENT);
      while (__hip_atomic_load(rel, __ATOMIC_RELAXED, __HIP_MEMORY_SCOPE_AGENT) < ep)
        __builtin_amdgcn_s_sleep(1);
    }
  }
  __syncthreads();
}

// ---------------- wave-per-tile GEMM, K=512, A fully in registers, optional in-reg LN --------
// 16x16 output per wave. A: Mx512 row-major; Bt: Nx512 row-major (normal-cached weights).
template<int LN, int COHA, int NTILE, int GELU_, int BIAS_, int RESID_, int ACCUM_,
         int OUTF_, int OUTB_>
__device__ __forceinline__ void gemm_reg16(
    const __bf16* __restrict__ A, const __bf16* __restrict__ Bt,
    int am0, int bn0, int bnstep,
    const float* __restrict__ lng, const float* __restrict__ lnb,
    const float* __restrict__ bias, const float* __restrict__ resid,
    const float* __restrict__ accum, float* __restrict__ outf,
    __bf16* __restrict__ outb, int ldo)
{
  const int lane = threadIdx.x & 63;
  const int kof = (lane >> 4) * 8;
  const __bf16* ap = A + (size_t)(am0 + (lane & 15)) * 512 + kof;
  bf16x8 a[16];
#pragma unroll
  for (int t = 0; t < 16; ++t) {
    if (COHA) {
      u64x2 q; q.x = cload8(ap + t * 32); q.y = cload8(ap + t * 32 + 4);
      a[t] = __builtin_bit_cast(bf16x8, q);
    } else {
      a[t] = *(const bf16x8*)(ap + t * 32);
    }
  }
  if (LN) {
    float s = 0.f, s2 = 0.f;
#pragma unroll
    for (int t = 0; t < 16; ++t)
#pragma unroll
      for (int j = 0; j < 8; ++j) { float f = (float)a[t][j]; s += f; s2 += f * f; }
    s += __shfl_xor(s, 16); s2 += __shfl_xor(s2, 16);
    s += __shfl_xor(s, 32); s2 += __shfl_xor(s2, 32);
    float mu = s * (1.f / 512.f);
    float rsg = rsqrtf(s2 * (1.f / 512.f) - mu * mu + 1e-5f);
#pragma unroll
    for (int t = 0; t < 16; ++t) {
      const int kb = t * 32 + kof;
      f32x4 g0 = *(const f32x4*)(lng + kb);
      f32x4 g1 = *(const f32x4*)(lng + kb + 4);
      f32x4 b0 = *(const f32x4*)(lnb + kb);
      f32x4 b1 = *(const f32x4*)(lnb + kb + 4);
#pragma unroll
      for (int j = 0; j < 4; ++j) {
        a[t][j]     = (__bf16)(((float)a[t][j]     - mu) * rsg * g0[j] + b0[j]);
        a[t][j + 4] = (__bf16)(((float)a[t][j + 4] - mu) * rsg * g1[j] + b1[j]);
      }
    }
  }
  for (int nt = 0; nt < NTILE; ++nt) {
    const int cb = bn0 + nt * bnstep;
    const __bf16* bp = Bt + (size_t)(cb + (lane & 15)) * 512 + kof;
    bf16x8 b[16];
#pragma unroll
    for (int t = 0; t < 16; ++t) b[t] = *(const bf16x8*)(bp + t * 32);
    f32x4 acc = {0.f, 0.f, 0.f, 0.f};
#pragma unroll
    for (int t = 0; t < 16; ++t)
      acc = __builtin_amdgcn_mfma_f32_16x16x32_bf16(a[t], b[t], acc, 0, 0, 0);
    const int col = cb + (lane & 15);
    const int row0 = am0 + (lane >> 4) * 4;
#pragma unroll
    for (int e = 0; e < 4; ++e) {
      const int r = row0 + e;
      float v = acc[e];
      if (BIAS_)  v += bias[col];
      if (RESID_) v += resid[r * 512 + col];
      if (GELU_)  v = gelu_f(v);
      if (ACCUM_) v += accum[r * 512 + col];
      if (OUTF_)  outf[r * 512 + col] = v;
      if (OUTB_)  cstore_bf16(outb + (size_t)r * ldo + col, (__bf16)v);
    }
  }
}

// ---------------- wave-per-tile GEMM, streaming K (depth-8), no LN ----------------
template<int KS, int COHA, int BIAS_, int RESID_, int ACCUM_, int OUTF_, int OUTB_>
__device__ __forceinline__ void gemm_stream(
    const __bf16* __restrict__ A, const __bf16* __restrict__ Bt,
    int am0, int bn0,
    const float* __restrict__ bias, const float* __restrict__ resid,
    const float* __restrict__ accum, float* __restrict__ outf,
    __bf16* __restrict__ outb, int ldo)
{
  const int lane = threadIdx.x & 63;
  const int kof = (lane >> 4) * 8;
  constexpr int K = KS * 32;
  const __bf16* ap = A + (size_t)(am0 + (lane & 15)) * K + kof;
  const __bf16* bp = Bt + (size_t)(bn0 + (lane & 15)) * K + kof;
  bf16x8 ra[8], rb[8];
#pragma unroll
  for (int s = 0; s < 8; ++s) {
    if (COHA) {
      u64x2 q; q.x = cload8(ap + s * 32); q.y = cload8(ap + s * 32 + 4);
      ra[s] = __builtin_bit_cast(bf16x8, q);
    } else {
      ra[s] = *(const bf16x8*)(ap + s * 32);
    }
    rb[s] = *(const bf16x8*)(bp + s * 32);
  }
  f32x4 acc = {0.f, 0.f, 0.f, 0.f};
#pragma unroll
  for (int t = 0; t < KS; ++t) {
    acc = __builtin_amdgcn_mfma_f32_16x16x32_bf16(ra[t & 7], rb[t & 7], acc, 0, 0, 0);
    if (t + 8 < KS) {
      const int u = t + 8;
      if (COHA) {
        u64x2 q; q.x = cload8(ap + u * 32); q.y = cload8(ap + u * 32 + 4);
        ra[t & 7] = __builtin_bit_cast(bf16x8, q);
      } else {
        ra[t & 7] = *(const bf16x8*)(ap + u * 32);
      }
      rb[t & 7] = *(const bf16x8*)(bp + u * 32);
    }
  }
  const int col = bn0 + (lane & 15);
  const int row0 = am0 + (lane >> 4) * 4;
#pragma unroll
  for (int e = 0; e < 4; ++e) {
    const int r = row0 + e;
    float v = acc[e];
    if (BIAS_)  v += bias[col];
    if (RESID_) v += resid[r * 512 + col];
    if (ACCUM_) v += accum[r * 512 + col];
    if (OUTF_)  outf[r * 512 + col] = v;
    if (OUTB_)  cstore_bf16(outb + (size_t)r * ldo + col, (__bf16)v);
  }
}

// ---------------- persistent mega kernel: 4 decoupled row-group chains ----------------
__global__ __launch_bounds__(256) void mega_kernel(
    const __bf16* __restrict__ xy_b, const __bf16* __restrict__ WcabT,
    const __bf16* __restrict__ WccT, const __bf16* __restrict__ WeffT,
    const __bf16* __restrict__ w1T, const __bf16* __restrict__ w2T,
    const float* __restrict__ bc, const float* __restrict__ beff,
    const float* __restrict__ ln1g, const float* __restrict__ ln1b,
    const float* __restrict__ ln2g, const float* __restrict__ ln2b,
    const float* __restrict__ b1f, const float* __restrict__ b2f,
    float* base_f, float* c_f, __bf16* c_b, float* x_f,
    __bf16* xb2, __bf16* xb4, __bf16* u_b, float* z_f, __bf16* z_b,
    float* out, int* bar)
{
  const int wg = blockIdx.x;
  const int g = wg >> 4, lg = wg & 15;
  const int wv = lg * 4 + (threadIdx.x >> 6);   // 0..63 within group
  const int sr = wv >> 5, ct = wv & 31;
  const int am0 = g * 32 + sr * 16;             // 16-row slice owned by this wave
  const int bn = ct * 16;                       // 16-col tile
  int* slots = bar + g * 512;
  int* rel   = bar + 2048 + g * 32;
  int ep = 0;

  // base = xy @ Wcab + bc   (xy from aux: kernel boundary -> normal loads safe)
  gemm_stream<32, 0, 1, 0, 0, 1, 1>(xy_b, WcabT, am0, bn, bc, nullptr, nullptr,
                                    base_f, c_b, 512);
  groupbar(slots, rel, lg, ++ep);

  for (int r = 0; r < 6; ++r) {
    if (r > 0) {  // S1: c = base + z @ Wcc
      gemm_reg16<0, 1, 1, 0, 0, 1, 0, 1, 1>(z_b, WccT, am0, bn, 0,
          nullptr, nullptr, nullptr, base_f, nullptr, c_f, c_b, 512);
      groupbar(slots, rel, lg, ++ep);
    }
    for (int l = 0; l < 2; ++l) {
      const __bf16* Ain = (l == 0) ? c_b : xb4;
      const float*  Rin = (l == 0) ? ((r > 0) ? c_f : base_f) : x_f;
      const int lo = l * 512;
      // S2: x = resid + LN1(A) @ Weff + beff
      gemm_reg16<1, 1, 1, 0, 1, 1, 0, 1, 1>(Ain, WeffT + l * 262144, am0, bn, 0,
          ln1g + lo, ln1b + lo, beff + lo, Rin, nullptr, x_f, xb2, 512);
      groupbar(slots, rel, lg, ++ep);
      // S3: u = gelu(LN2(x) @ w1 + b1)  — 4 col-tiles per wave, A/stats loaded once
      gemm_reg16<1, 1, 4, 1, 1, 0, 0, 0, 1>(xb2, w1T + l * 1048576, am0, bn, 512,
          ln2g + lo, ln2b + lo, b1f + l * 2048, nullptr, nullptr, nullptr, u_b, 2048);
      groupbar(slots, rel, lg, ++ep);
      // S4: x = x + u @ w2 + b2 ; layer 1 accumulates into z (r==5 -> d_out)
      if (l == 0) {
        gemm_stream<64, 1, 1, 1, 0, 1, 1>(u_b, w2T, am0, bn, b2f, x_f, nullptr,
                                          x_f, xb4, 512);
        groupbar(slots, rel, lg, ++ep);
      } else if (r == 0) {
        gemm_stream<64, 1, 1, 1, 0, 1, 1>(u_b, w2T + 1048576, am0, bn, b2f + 512,
                                          x_f, nullptr, z_f, z_b, 512);
        groupbar(slots, rel, lg, ++ep);
      } else if (r < 5) {
        gemm_stream<64, 1, 1, 1, 1, 1, 1>(u_b, w2T + 1048576, am0, bn, b2f + 512,
                                          x_f, z_f, z_f, z_b, 512);
        groupbar(slots, rel, lg, ++ep);
      } else {
        gemm_stream<64, 1, 1, 1, 1, 1, 0>(u_b, w2T + 1048576, am0, bn, b2f + 512,
                                          x_f, z_f, out, nullptr, 512);
      }
    }
  }
}

extern "C" void kernel_launch(void* const* d_in, const int* in_sizes, int n_in,
                              void* d_out, int out_size, void* d_ws, size_t ws_size,
                              hipStream_t stream) {
  const float* x_encoded = (const float*)d_in[0];
  const float* y_current = (const float*)d_in[1];
  const float* Wpi  = (const float*)d_in[2];
  const float* bpi  = (const float*)d_in[3];
  const float* Wpa  = (const float*)d_in[4];
  const float* bpa  = (const float*)d_in[5];
  const float* Wc   = (const float*)d_in[6];
  const float* bc   = (const float*)d_in[7];
  const float* ln1g = (const float*)d_in[8];
  const float* ln1b = (const float*)d_in[9];
  const float* wqkv = (const float*)d_in[10];
  const float* bqkv = (const float*)d_in[11];
  const float* wo   = (const float*)d_in[12];
  const float* bo   = (const float*)d_in[13];
  const float* ln2g = (const float*)d_in[14];
  const float* ln2b = (const float*)d_in[15];
  const float* w1f  = (const float*)d_in[16];
  const float* b1f  = (const float*)d_in[17];
  const float* w2f  = (const float*)d_in[18];
  const float* b2f  = (const float*)d_in[19];
  (void)in_sizes; (void)n_in; (void)out_size; (void)ws_size;

  char* wsb = (char*)d_ws;
  size_t off = 0;
  auto carve = [&](size_t bytes) -> void* {
    void* p = wsb + off;
    off += (bytes + 255) & ~(size_t)255;
    return p;
  };
  __bf16* xp_b    = (__bf16*)carve(131072 * 2);
  __bf16* y_b     = (__bf16*)carve(32768 * 2);
  __bf16* WpiT    = (__bf16*)carve(524288 * 2);
  __bf16* WpaT    = (__bf16*)carve(131072 * 2);
  __bf16* WcabT   = (__bf16*)carve(524288 * 2);
  __bf16* WccT    = (__bf16*)carve(262144 * 2);
  __bf16* w1T     = (__bf16*)carve(2097152 * 2);
  __bf16* w2T     = (__bf16*)carve(2097152 * 2);
  __bf16* woT     = (__bf16*)carve(524288 * 2);
  __bf16* Wv_b    = (__bf16*)carve(524288 * 2);
  __bf16* WeffT   = (__bf16*)carve(524288 * 2);
  float*  beff    = (float*) carve(1024 * 4);
  __bf16* xy_b    = (__bf16*)carve(131072 * 2);
  float*  base_f  = (float*) carve(65536 * 4);
  float*  c_f     = (float*) carve(65536 * 4);
  __bf16* c_b     = (__bf16*)carve(65536 * 2);
  float*  x_f     = (float*) carve(65536 * 4);
  __bf16* xb2     = (__bf16*)carve(65536 * 2);
  __bf16* xb4     = (__bf16*)carve(65536 * 2);
  __bf16* u_b     = (__bf16*)carve(262144 * 2);
  float*  z_f     = (float*) carve(65536 * 4);
  __bf16* z_b     = (__bf16*)carve(65536 * 2);
  int*    d_bar   = (int*)   carve(16384);

  hipMemsetAsync(d_bar, 0, 16384, stream);
  prep_kernel<<<6804, 256, 0, stream>>>(x_encoded, Wpi, Wpa, Wc, w1f, w2f, wo,
      wqkv, y_current, bqkv, bo, xp_b, WpiT, WpaT, WcabT, WccT, w1T, w2T, woT,
      Wv_b, y_b, beff);
  aux_kernel<<<640, 256, 0, stream>>>(woT, Wv_b, xp_b, y_b, WpiT, WpaT,
      bpi, bpa, WeffT, xy_b);
  mega_kernel<<<64, 256, 0, stream>>>(
      xy_b, WcabT, WccT, WeffT, w1T, w2T, bc, beff,
      ln1g, ln1b, ln2g, ln2b, b1f, b2f,
      base_f, c_f, c_b, x_f, xb2, xb4, u_b, z_f, z_b,
      (float*)d_out, d_bar);
}